// Round 1
// baseline (275.864 us; speedup 1.0000x reference)
//
#include <hip/hip_runtime.h>
#include <hip/hip_bf16.h>

#define BB 4
#define LL 2048
#define DD 512
#define DKK 256

typedef __bf16 bf16;
typedef __bf16 bf16x4 __attribute__((ext_vector_type(4)));
typedef __bf16 bf16x8 __attribute__((ext_vector_type(8)));
typedef float f32x4 __attribute__((ext_vector_type(4)));

__device__ __forceinline__ void async_ld16(const bf16* g, bf16* l) {
    __builtin_amdgcn_global_load_lds(
        (const __attribute__((address_space(1))) void*)g,
        (__attribute__((address_space(3))) void*)l, 16, 0, 0);
}

__global__ void conv_f32_bf16v(const float* __restrict__ in, bf16* __restrict__ out, int n4) {
    int i = blockIdx.x * 256 + threadIdx.x;
    if (i < n4) {
        f32x4 v = *(const f32x4*)(in + (size_t)i * 4);
        bf16x4 o;
        #pragma unroll
        for (int j = 0; j < 4; ++j) o[j] = (bf16)v[j];
        *(bf16x4*)(out + (size_t)i * 4) = o;
    }
}

__global__ void transpose_f32_bf16(const float* __restrict__ in, bf16* __restrict__ out,
                                   int R, int C) {
    int idx = blockIdx.x * 256 + threadIdx.x;
    if (idx < R * C) {
        int r = idx / C, c = idx % C;
        out[(size_t)c * R + r] = (bf16)in[idx];
    }
}

// 64x64-tile bf16 transpose: in [R][C] -> out [C][R], coalesced both sides.
__global__ void transpose_bf16_tile(const bf16* __restrict__ in, bf16* __restrict__ out,
                                    int R, int C) {
    __shared__ bf16 t[64][72];
    int tcx = C >> 6;
    int bx = blockIdx.x % tcx, by = blockIdx.x / tcx;
    int r = threadIdx.x >> 2, cc = (threadIdx.x & 3) * 16;
    const bf16* src = in + (size_t)(by * 64 + r) * C + bx * 64 + cc;
    bf16x8 v0 = *(const bf16x8*)src;
    bf16x8 v1 = *(const bf16x8*)(src + 8);
    #pragma unroll
    for (int u = 0; u < 8; ++u) { t[cc + u][r] = v0[u]; t[cc + 8 + u][r] = v1[u]; }
    __syncthreads();
    bf16* dst = out + (size_t)(bx * 64 + r) * R + by * 64 + cc;
    *(bf16x8*)dst = *(const bf16x8*)&t[r][cc];
    *(bf16x8*)(dst + 8) = *(const bf16x8*)&t[r][cc + 8];
}

// Unified bf16 GEMM, m97-style: C[m][n] = sum_k A[m][k]*B[n][k].  128x128 tile,
// 4 waves (each 64x64 = 4x4 acc).  A and B staged direct-to-LDS via
// global_load_lds(16B) with parity-rotation swizzle: chunk c of row r stored at
// slot (c + (r>>1))&3 -> frag reads hit 8 slot-parity combos = 2 lanes/bank (free).
// SKEW=1: scatter-store into skewed Srel layout:
//   QE[r][c] -> (c >= L-1-r) ? Srel[r][c-(L-1-r)] : (r>=1 ? Srel[r-1][c+r+1] : drop)
template <int SKEW>
__launch_bounds__(256, 2)
__global__ void gemm128(const bf16* __restrict__ A, const bf16* __restrict__ B,
                        bf16* __restrict__ C, int N, int K,
                        long aStride, long cStride)
{
    __shared__ bf16 Als[128 * 32];
    __shared__ bf16 Bls[128 * 32];

    int tid  = threadIdx.x;
    int lane = tid & 63;
    int wid  = tid >> 6;
    int l15  = lane & 15;
    int quad = lane >> 4;
    int nb = N >> 7;
    int gx = blockIdx.x % nb;
    int gy = blockIdx.x / nb;

    const bf16* Ab = A + (size_t)blockIdx.y * aStride + (size_t)gy * 128 * K;
    const bf16* Bb = B + (size_t)gx * 128 * K;

    int rl = lane >> 2;     // staging: row within 16-row inst
    int sl = lane & 3;      // staging: slot
    int half = wid & 1;     // waves 0/2: rows 0-63; waves 1/3: rows 64-127
    const bf16* gsrc = (wid < 2) ? Ab : Bb;
    bf16* ldst = (wid < 2) ? Als : Bls;

    f32x4 acc[4][4];
    #pragma unroll
    for (int i = 0; i < 4; ++i)
        #pragma unroll
        for (int j = 0; j < 4; ++j) acc[i][j] = 0;

    for (int k0 = 0; k0 < K; k0 += 32) {
        #pragma unroll
        for (int u = 0; u < 4; ++u) {
            int inst = half * 4 + u;
            int row  = inst * 16 + rl;
            int c    = (sl - (row >> 1)) & 3;
            async_ld16(gsrc + (size_t)row * K + k0 + c * 8, ldst + inst * 512);
        }
        __syncthreads();   // drains vmcnt(0): staging complete
        bf16x8 fA[4], fB[4];
        #pragma unroll
        for (int rt = 0; rt < 4; ++rt) {
            int row = (wid & 1) * 64 + rt * 16 + l15;
            int s   = (quad + (row >> 1)) & 3;
            fA[rt] = *(const bf16x8*)&Als[row * 32 + s * 8];
        }
        #pragma unroll
        for (int ct = 0; ct < 4; ++ct) {
            int col = (wid >> 1) * 64 + ct * 16 + l15;
            int s   = (quad + (col >> 1)) & 3;
            fB[ct] = *(const bf16x8*)&Bls[col * 32 + s * 8];
        }
        #pragma unroll
        for (int rt = 0; rt < 4; ++rt)
            #pragma unroll
            for (int ct = 0; ct < 4; ++ct)
                acc[rt][ct] = __builtin_amdgcn_mfma_f32_16x16x32_bf16(
                                  fA[rt], fB[ct], acc[rt][ct], 0, 0, 0);
        __syncthreads();   // LDS reuse guard
    }

    bf16* Cb = C + (size_t)blockIdx.y * cStride;
    int m0 = gy * 128 + (wid & 1) * 64;
    int n0 = gx * 128 + (wid >> 1) * 64;
    if (!SKEW) {
        #pragma unroll
        for (int rt = 0; rt < 4; ++rt)
            #pragma unroll
            for (int ct = 0; ct < 4; ++ct)
                #pragma unroll
                for (int r = 0; r < 4; ++r) {
                    int m = m0 + rt * 16 + quad * 4 + r;
                    int n = n0 + ct * 16 + l15;
                    Cb[(size_t)m * N + n] = (bf16)acc[rt][ct][r];
                }
    } else {
        #pragma unroll
        for (int rt = 0; rt < 4; ++rt)
            #pragma unroll
            for (int ct = 0; ct < 4; ++ct)
                #pragma unroll
                for (int r = 0; r < 4; ++r) {
                    int row = m0 + rt * 16 + quad * 4 + r;
                    int c   = n0 + ct * 16 + l15;
                    bool lower = (c >= LL - 1 - row);
                    int dr = lower ? row : row - 1;
                    int dc = lower ? c - (LL - 1 - row) : c + row + 1;
                    if (lower || row >= 1)
                        Cb[(size_t)dr * LL + dc] = (bf16)acc[rt][ct][r];
                }
    }
}

// Fused attention, R8 structure: K/V staging is WAVE-LOCAL (wave w stages and
// reads exactly K rows [16w,16w+16) / V rows [64w,64w+64)), so the staging
// barrier (old b1) and the LDS-reuse barrier (old b4) are unnecessary.
// Loop is now 2 raw s_barriers/iter (Ss handoff, Ps handoff) with the K/V
// global_load_lds for iter i+1 issued during QK(i) (counted-vmcnt style: the
// barriers do NOT drain vmcnt).  V fragments are pre-read into regs in the QK
// phase so the next V staging can be issued a full iteration ahead.  Srel tile
// is prefetched one iteration ahead into registers (hides HBM latency).
// Ss pad 68->65 (stride ≡ 1 mod 32): softmax reads go 8-way -> 2-way conflict.
__launch_bounds__(256, 2)
__global__ void attn_kernel(const bf16* __restrict__ Qw, const bf16* __restrict__ Kw,
                            const bf16* __restrict__ Vt, const bf16* __restrict__ Srel,
                            float* __restrict__ out)
{
    __shared__ bf16  Klds[64 * 256];      // rows j (64), 32 chunks of 8, rotated
    __shared__ bf16  Vlds[256 * 64];      // rows d (256), 8 chunks of 8, rotated
    __shared__ float Ss[32][65];
    __shared__ bf16  Ps[32][72];
    __shared__ float mSt[32], lSt[32], aSt[32];

    int tid  = threadIdx.x;
    int lane = tid & 63;
    int wid  = tid >> 6;
    int l15  = lane & 15;
    int quad = lane >> 4;

    int xcd = blockIdx.x & 7;          // XCD = blockIdx % 8 (round-robin dispatch)
    int b   = xcd >> 1;
    int dh  = xcd & 1;
    int i0  = (blockIdx.x >> 3) * 32;

    const bf16* Qb = Qw + (size_t)b * LL * DKK;
    const bf16* Kb = Kw + (size_t)b * LL * DKK;
    const bf16* Sb = Srel + (size_t)b * LL * LL;
    const bf16* Vb = Vt + (size_t)(dh * 256) * (BB * LL) + (size_t)b * LL;

    bf16x8 Qreg[2][8];
    #pragma unroll
    for (int rt = 0; rt < 2; ++rt)
        #pragma unroll
        for (int ks = 0; ks < 8; ++ks)
            Qreg[rt][ks] = *(const bf16x8*)(Qb + (size_t)(i0 + rt * 16 + l15) * DKK
                                            + ks * 32 + quad * 8);

    if (tid < 32) { mSt[tid] = -1e30f; lSt[tid] = 0.f; }

    f32x4 accO[2][4];
    #pragma unroll
    for (int rt = 0; rt < 2; ++rt)
        #pragma unroll
        for (int nt = 0; nt < 4; ++nt) accO[rt][nt] = 0;

    // ---- prologue: stage tile 0 (wave-local) + prefetch Srel tile 0 ----
    #pragma unroll
    for (int u = 0; u < 8; ++u) {
        int inst = wid * 8 + u;
        int s = inst * 64 + lane;
        int j = s >> 5, cp = lane & 31;
        int c = (cp - j) & 31;
        async_ld16(Kb + (size_t)j * DKK + c * 8, Klds + inst * 512);
    }
    #pragma unroll
    for (int u = 0; u < 8; ++u) {
        int inst = wid * 8 + u;
        int s = inst * 64 + lane;
        int d = s >> 3, cp = lane & 7;
        int c = (cp - d) & 7;
        async_ld16(Vb + (size_t)d * (BB * LL) + c * 8, Vlds + inst * 512);
    }
    int srow = i0 + (tid >> 3);
    int ssg  = tid & 7;
    bf16x8 srelCur = *(const bf16x8*)(Sb + (size_t)srow * LL + ssg * 8);

    for (int j0 = 0; j0 < LL; j0 += 64) {
        int jn = (j0 + 64) & (LL - 1);   // next tile (wraps to 0 on last iter: dummy)

        // ---- wait current tile staged (wave-local; no barrier) ----
        asm volatile("s_waitcnt vmcnt(0)" ::: "memory");
        __builtin_amdgcn_sched_barrier(0);

        // ---- read K fragments (this iter) and V fragments (for PV phase) ----
        bf16x8 kf[8];
        int jrow = wid * 16 + l15;
        #pragma unroll
        for (int ks = 0; ks < 8; ++ks) {
            int cp = (ks * 4 + quad + jrow) & 31;
            kf[ks] = *(const bf16x8*)&Klds[jrow * 256 + cp * 8];
        }
        bf16x8 vf[4][2];
        #pragma unroll
        for (int nt = 0; nt < 4; ++nt) {
            int dd = wid * 64 + nt * 16 + l15;
            int c0 = (quad + dd) & 7;
            int c1 = (4 + quad + dd) & 7;
            vf[nt][0] = *(const bf16x8*)&Vlds[dd * 64 + c0 * 8];
            vf[nt][1] = *(const bf16x8*)&Vlds[dd * 64 + c1 * 8];
        }
        // WAR guard: all LDS reads into regs complete before next-tile DMA issues
        asm volatile("s_waitcnt lgkmcnt(0)" ::: "memory");
        __builtin_amdgcn_sched_barrier(0);

        // ---- issue next-tile staging (wave-local regions; stays in flight
        //      across both barriers, drained at next iter's vmcnt(0)) ----
        #pragma unroll
        for (int u = 0; u < 8; ++u) {
            int inst = wid * 8 + u;
            int s = inst * 64 + lane;
            int j = s >> 5, cp = lane & 31;
            int c = (cp - j) & 31;
            async_ld16(Kb + (size_t)(jn + j) * DKK + c * 8, Klds + inst * 512);
        }
        #pragma unroll
        for (int u = 0; u < 8; ++u) {
            int inst = wid * 8 + u;
            int s = inst * 64 + lane;
            int d = s >> 3, cp = lane & 7;
            int c = (cp - d) & 7;
            async_ld16(Vb + (size_t)d * (BB * LL) + jn + c * 8, Vlds + inst * 512);
        }

        // ---- QK^T ----
        {
            f32x4 s0 = 0, s1 = 0;
            __builtin_amdgcn_s_setprio(1);
            #pragma unroll
            for (int ks = 0; ks < 8; ++ks) {
                s0 = __builtin_amdgcn_mfma_f32_16x16x32_bf16(Qreg[0][ks], kf[ks], s0, 0, 0, 0);
                s1 = __builtin_amdgcn_mfma_f32_16x16x32_bf16(Qreg[1][ks], kf[ks], s1, 0, 0, 0);
            }
            __builtin_amdgcn_s_setprio(0);
            #pragma unroll
            for (int r = 0; r < 4; ++r) {
                Ss[quad * 4 + r][wid * 16 + l15]      = s0[r];
                Ss[16 + quad * 4 + r][wid * 16 + l15] = s1[r];
            }
        }
        asm volatile("s_waitcnt lgkmcnt(0)" ::: "memory");
        __builtin_amdgcn_s_barrier();                       // b2: Ss handoff

        // ---- softmax (thread-remapped: row r = tid>>3, seg sg = tid&7) ----
        {
            int r = tid >> 3, sg = tid & 7;
            int i = i0 + r;
            bf16x8 s8 = srelCur;
            float v[8];
            #pragma unroll
            for (int c = 0; c < 8; ++c) {
                float sr = (j0 + sg * 8 + c == i + 1) ? 0.f : (float)s8[c];
                v[c] = (Ss[r][sg * 8 + c] + sr) * 0.0625f;
            }
            // prefetch next iter's Srel tile (consumed after next vmcnt(0))
            srelCur = *(const bf16x8*)(Sb + (size_t)srow * LL + jn + ssg * 8);
            float tmax = v[0];
            #pragma unroll
            for (int c = 1; c < 8; ++c) tmax = fmaxf(tmax, v[c]);
            tmax = fmaxf(tmax, __shfl_xor(tmax, 1));
            tmax = fmaxf(tmax, __shfl_xor(tmax, 2));
            tmax = fmaxf(tmax, __shfl_xor(tmax, 4));
            float mOld = mSt[r], lOld = lSt[r];
            float mNew = fmaxf(mOld, tmax);
            float alpha = __expf(mOld - mNew);
            float ps = 0.f;
            bf16x8 pv;
            #pragma unroll
            for (int c = 0; c < 8; ++c) {
                float p = __expf(v[c] - mNew);
                ps += p;
                pv[c] = (bf16)p;
            }
            ps += __shfl_xor(ps, 1);
            ps += __shfl_xor(ps, 2);
            ps += __shfl_xor(ps, 4);
            *(bf16x8*)&Ps[r][sg * 8] = pv;
            if (sg == 0) { mSt[r] = mNew; lSt[r] = alpha * lOld + ps; aSt[r] = alpha; }
        }
        asm volatile("s_waitcnt lgkmcnt(0)" ::: "memory");
        __builtin_amdgcn_s_barrier();                       // b3: Ps handoff

        // ---- PV (V fragments already in regs) ----
        {
            bf16x8 aF[2][2];
            #pragma unroll
            for (int rt = 0; rt < 2; ++rt)
                #pragma unroll
                for (int kk = 0; kk < 2; ++kk)
                    aF[rt][kk] = *(const bf16x8*)&Ps[rt * 16 + l15][kk * 32 + quad * 8];
            float ar[2][4];
            #pragma unroll
            for (int rt = 0; rt < 2; ++rt)
                #pragma unroll
                for (int r = 0; r < 4; ++r) ar[rt][r] = aSt[rt * 16 + quad * 4 + r];
            __builtin_amdgcn_s_setprio(1);
            #pragma unroll
            for (int nt = 0; nt < 4; ++nt) {
                #pragma unroll
                for (int rt = 0; rt < 2; ++rt) {
                    f32x4 o = accO[rt][nt];
                    o[0] *= ar[rt][0]; o[1] *= ar[rt][1];
                    o[2] *= ar[rt][2]; o[3] *= ar[rt][3];
                    o = __builtin_amdgcn_mfma_f32_16x16x32_bf16(aF[rt][0], vf[nt][0], o, 0, 0, 0);
                    o = __builtin_amdgcn_mfma_f32_16x16x32_bf16(aF[rt][1], vf[nt][1], o, 0, 0, 0);
                    accO[rt][nt] = o;
                }
            }
            __builtin_amdgcn_s_setprio(0);
        }
        // no trailing barrier: Ss WAR covered by b3, Ps/aSt WAR covered by next b2
    }
    float lr[2][4];
    #pragma unroll
    for (int rt = 0; rt < 2; ++rt)
        #pragma unroll
        for (int r = 0; r < 4; ++r) lr[rt][r] = 1.f / lSt[rt * 16 + quad * 4 + r];
    #pragma unroll
    for (int rt = 0; rt < 2; ++rt)
        #pragma unroll
        for (int nt = 0; nt < 4; ++nt)
            #pragma unroll
            for (int r = 0; r < 4; ++r) {
                int i = i0 + rt * 16 + quad * 4 + r;
                int d = dh * 256 + wid * 64 + nt * 16 + l15;
                out[((size_t)b * LL + i) * DD + d] = accO[rt][nt][r] * lr[rt][r];
            }
}

extern "C" void kernel_launch(void* const* d_in, const int* in_sizes, int n_in,
                              void* d_out, int out_size, void* d_ws, size_t ws_size,
                              hipStream_t stream) {
    const float* inQ = (const float*)d_in[0];
    const float* inK = (const float*)d_in[1];
    const float* inV = (const float*)d_in[2];
    const float* Wq  = (const float*)d_in[3];
    const float* Wk  = (const float*)d_in[4];
    const float* Wv  = (const float*)d_in[5];
    const float* E   = (const float*)d_in[6];
    float* out = (float*)d_out;

    char* ws = (char*)d_ws;
    bf16* Qw   = (bf16*)(ws);                         // 4 MB  [B*L][DK]
    bf16* Kw   = (bf16*)(ws + ((size_t)4  << 20));    // 4 MB  [B*L][DK]
    bf16* Vt   = (bf16*)(ws + ((size_t)8  << 20));    // 8 MB  [D][B*L]
    bf16* SrelW= (bf16*)(ws + ((size_t)16 << 20));    // 32 MB [B,L,L] skewed
    // transient buffers inside the Srel region (dead before QE writes Srel):
    bf16* Xq   = (bf16*)(ws + ((size_t)16 << 20));    // 8 MB  inQ as bf16
    bf16* Xk   = (bf16*)(ws + ((size_t)24 << 20));    // 8 MB
    bf16* Xv   = (bf16*)(ws + ((size_t)32 << 20));    // 8 MB
    bf16* Vw   = (bf16*)(ws + ((size_t)40 << 20));    // 8 MB  V row-major
    bf16* WqT  = (bf16*)(ws + ((size_t)48 << 20));            // [DK][D]
    bf16* WkT  = (bf16*)(ws + ((size_t)48 << 20) + 262144);   // [DK][D]
    bf16* WvT  = (bf16*)(ws + ((size_t)48 << 20) + 524288);   // [D][D]
    bf16* Eb   = (bf16*)(ws + ((size_t)49 << 20));            // [L][DK]

    conv_f32_bf16v<<<4096, 256, 0, stream>>>(inQ, Xq, (BB * LL * DD) / 4);
    conv_f32_bf16v<<<4096, 256, 0, stream>>>(inK, Xk, (BB * LL * DD) / 4);
    conv_f32_bf16v<<<4096, 256, 0, stream>>>(inV, Xv, (BB * LL * DD) / 4);
    conv_f32_bf16v<<<512,  256, 0, stream>>>(E, Eb, (LL * DKK) / 4);
    transpose_f32_bf16<<<512,  256, 0, stream>>>(Wq, WqT, DD, DKK);
    transpose_f32_bf16<<<512,  256, 0, stream>>>(Wk, WkT, DD, DKK);
    transpose_f32_bf16<<<1024, 256, 0, stream>>>(Wv, WvT, DD, DD);

    // Q = Xq·Wq^T': M=8192 N=256 K=512
    gemm128<0><<<dim3(2 * 64, 1),  256, 0, stream>>>(Xq, WqT, Qw, DKK, DD, 0, 0);
    gemm128<0><<<dim3(2 * 64, 1),  256, 0, stream>>>(Xk, WkT, Kw, DKK, DD, 0, 0);
    // Vw = Xv·Wv^T': M=8192 N=512 K=512
    gemm128<0><<<dim3(4 * 64, 1),  256, 0, stream>>>(Xv, WvT, Vw, DD, DD, 0, 0);
    // Vt = Vw^T  [512][8192]
    transpose_bf16_tile<<<(DD / 64) * (BB * LL / 64), 256, 0, stream>>>(Vw, Vt, BB * LL, DD);
    // Srel (skewed) = skew(Q·E^T): per-batch M=N=2048 K=256
    gemm128<1><<<dim3(16 * 16, BB), 256, 0, stream>>>(Qw, Eb, SrelW, LL, DKK,
                                                      (long)LL * DKK, (long)LL * LL);
    attn_kernel<<<dim3(BB * 64 * 2), 256, 0, stream>>>(Qw, Kw, Vt, SrelW, out);
}

// Round 2
// 238.246 us; speedup vs baseline: 1.1579x; 1.1579x over previous
//
#include <hip/hip_runtime.h>
#include <hip/hip_bf16.h>

#define BB 4
#define LL 2048
#define DD 512
#define DKK 256

typedef __bf16 bf16;
typedef __bf16 bf16x4 __attribute__((ext_vector_type(4)));
typedef __bf16 bf16x8 __attribute__((ext_vector_type(8)));
typedef float f32x4 __attribute__((ext_vector_type(4)));

__device__ __forceinline__ void async_ld16(const bf16* g, bf16* l) {
    __builtin_amdgcn_global_load_lds(
        (const __attribute__((address_space(1))) void*)g,
        (__attribute__((address_space(3))) void*)l, 16, 0, 0);
}

// fused bf16 conversion of the three [B,L,D] activations (one launch)
__global__ void conv3_f32_bf16(const float* __restrict__ a, const float* __restrict__ bq,
                               const float* __restrict__ c,
                               bf16* __restrict__ oa, bf16* __restrict__ ob,
                               bf16* __restrict__ oc, int n4) {
    const float* in = (blockIdx.y == 0) ? a : (blockIdx.y == 1) ? bq : c;
    bf16* out = (blockIdx.y == 0) ? oa : (blockIdx.y == 1) ? ob : oc;
    int i = blockIdx.x * 256 + threadIdx.x;
    if (i < n4) {
        f32x4 v = *(const f32x4*)(in + (size_t)i * 4);
        bf16x4 o;
        #pragma unroll
        for (int j = 0; j < 4; ++j) o[j] = (bf16)v[j];
        *(bf16x4*)(out + (size_t)i * 4) = o;
    }
}

__global__ void conv_f32_bf16v(const float* __restrict__ in, bf16* __restrict__ out, int n4) {
    int i = blockIdx.x * 256 + threadIdx.x;
    if (i < n4) {
        f32x4 v = *(const f32x4*)(in + (size_t)i * 4);
        bf16x4 o;
        #pragma unroll
        for (int j = 0; j < 4; ++j) o[j] = (bf16)v[j];
        *(bf16x4*)(out + (size_t)i * 4) = o;
    }
}

__global__ void transpose_f32_bf16(const float* __restrict__ in, bf16* __restrict__ out,
                                   int R, int C) {
    int idx = blockIdx.x * 256 + threadIdx.x;
    if (idx < R * C) {
        int r = idx / C, c = idx % C;
        out[(size_t)c * R + r] = (bf16)in[idx];
    }
}

// 64x64-tile bf16 transpose: in [R][C] -> out [C][R], coalesced both sides.
__global__ void transpose_bf16_tile(const bf16* __restrict__ in, bf16* __restrict__ out,
                                    int R, int C) {
    __shared__ bf16 t[64][72];
    int tcx = C >> 6;
    int bx = blockIdx.x % tcx, by = blockIdx.x / tcx;
    int r = threadIdx.x >> 2, cc = (threadIdx.x & 3) * 16;
    const bf16* src = in + (size_t)(by * 64 + r) * C + bx * 64 + cc;
    bf16x8 v0 = *(const bf16x8*)src;
    bf16x8 v1 = *(const bf16x8*)(src + 8);
    #pragma unroll
    for (int u = 0; u < 8; ++u) { t[cc + u][r] = v0[u]; t[cc + 8 + u][r] = v1[u]; }
    __syncthreads();
    bf16* dst = out + (size_t)(bx * 64 + r) * R + by * 64 + cc;
    *(bf16x8*)dst = *(const bf16x8*)&t[r][cc];
    *(bf16x8*)(dst + 8) = *(const bf16x8*)&t[r][cc + 8];
}

// Unified bf16 GEMM, m97-style: C[m][n] = sum_k A[m][k]*B[n][k].  128x128 tile,
// 4 waves (each 64x64 = 4x4 acc).  A and B staged direct-to-LDS via
// global_load_lds(16B) with parity-rotation swizzle.  bStride lets blockIdx.y
// batch over different B operands (Q+K fused launch).
// SKEW=1: scatter-store into skewed Srel layout.
template <int SKEW>
__launch_bounds__(256, 2)
__global__ void gemm128(const bf16* __restrict__ A, const bf16* __restrict__ B,
                        bf16* __restrict__ C, int N, int K,
                        long aStride, long bStride, long cStride)
{
    __shared__ bf16 Als[128 * 32];
    __shared__ bf16 Bls[128 * 32];

    int tid  = threadIdx.x;
    int lane = tid & 63;
    int wid  = tid >> 6;
    int l15  = lane & 15;
    int quad = lane >> 4;
    int nb = N >> 7;
    int gx = blockIdx.x % nb;
    int gy = blockIdx.x / nb;

    const bf16* Ab = A + (size_t)blockIdx.y * aStride + (size_t)gy * 128 * K;
    const bf16* Bb = B + (size_t)blockIdx.y * bStride + (size_t)gx * 128 * K;

    int rl = lane >> 2;     // staging: row within 16-row inst
    int sl = lane & 3;      // staging: slot
    int half = wid & 1;     // waves 0/2: rows 0-63; waves 1/3: rows 64-127
    const bf16* gsrc = (wid < 2) ? Ab : Bb;
    bf16* ldst = (wid < 2) ? Als : Bls;

    f32x4 acc[4][4];
    #pragma unroll
    for (int i = 0; i < 4; ++i)
        #pragma unroll
        for (int j = 0; j < 4; ++j) acc[i][j] = 0;

    for (int k0 = 0; k0 < K; k0 += 32) {
        #pragma unroll
        for (int u = 0; u < 4; ++u) {
            int inst = half * 4 + u;
            int row  = inst * 16 + rl;
            int c    = (sl - (row >> 1)) & 3;
            async_ld16(gsrc + (size_t)row * K + k0 + c * 8, ldst + inst * 512);
        }
        __syncthreads();   // drains vmcnt(0): staging complete
        bf16x8 fA[4], fB[4];
        #pragma unroll
        for (int rt = 0; rt < 4; ++rt) {
            int row = (wid & 1) * 64 + rt * 16 + l15;
            int s   = (quad + (row >> 1)) & 3;
            fA[rt] = *(const bf16x8*)&Als[row * 32 + s * 8];
        }
        #pragma unroll
        for (int ct = 0; ct < 4; ++ct) {
            int col = (wid >> 1) * 64 + ct * 16 + l15;
            int s   = (quad + (col >> 1)) & 3;
            fB[ct] = *(const bf16x8*)&Bls[col * 32 + s * 8];
        }
        #pragma unroll
        for (int rt = 0; rt < 4; ++rt)
            #pragma unroll
            for (int ct = 0; ct < 4; ++ct)
                acc[rt][ct] = __builtin_amdgcn_mfma_f32_16x16x32_bf16(
                                  fA[rt], fB[ct], acc[rt][ct], 0, 0, 0);
        __syncthreads();   // LDS reuse guard
    }

    bf16* Cb = C + (size_t)blockIdx.y * cStride;
    int m0 = gy * 128 + (wid & 1) * 64;
    int n0 = gx * 128 + (wid >> 1) * 64;
    if (!SKEW) {
        #pragma unroll
        for (int rt = 0; rt < 4; ++rt)
            #pragma unroll
            for (int ct = 0; ct < 4; ++ct)
                #pragma unroll
                for (int r = 0; r < 4; ++r) {
                    int m = m0 + rt * 16 + quad * 4 + r;
                    int n = n0 + ct * 16 + l15;
                    Cb[(size_t)m * N + n] = (bf16)acc[rt][ct][r];
                }
    } else {
        #pragma unroll
        for (int rt = 0; rt < 4; ++rt)
            #pragma unroll
            for (int ct = 0; ct < 4; ++ct)
                #pragma unroll
                for (int r = 0; r < 4; ++r) {
                    int row = m0 + rt * 16 + quad * 4 + r;
                    int c   = n0 + ct * 16 + l15;
                    bool lower = (c >= LL - 1 - row);
                    int dr = lower ? row : row - 1;
                    int dc = lower ? c - (LL - 1 - row) : c + row + 1;
                    if (lower || row >= 1)
                        Cb[(size_t)dr * LL + dc] = (bf16)acc[rt][ct][r];
                }
    }
}

// K(i+1) staging: wave-local rows [16w,16w+16) of Klds
#define STAGE_K(JT) do {                                                        \
    _Pragma("unroll")                                                           \
    for (int u_ = 0; u_ < 8; ++u_) {                                            \
        int inst_ = wid * 8 + u_;                                               \
        int j_ = inst_ * 2 + (lane >> 5);                                       \
        int cp_ = lane & 31;                                                    \
        int c_ = (cp_ - j_) & 31;                                               \
        async_ld16(Kb + (size_t)((JT) + j_) * DKK + c_ * 8, Klds + inst_ * 512);\
    } } while (0)

// V(i+1) staging: wave-local rows [64w,64w+64) of Vlds
#define STAGE_V(JT) do {                                                        \
    _Pragma("unroll")                                                           \
    for (int u_ = 0; u_ < 8; ++u_) {                                            \
        int inst_ = wid * 8 + u_;                                               \
        int d_ = inst_ * 8 + (lane >> 3);                                       \
        int cp_ = lane & 7;                                                     \
        int c_ = (cp_ - d_) & 7;                                                \
        async_ld16(Vb + (size_t)d_ * (BB * LL) + (JT) + c_ * 8,                 \
                   Vlds + inst_ * 512);                                         \
    } } while (0)

// Fused attention, R9: R7 phase order + one-ahead SPLIT staging with counted
// vmcnt.  K(i+1) issued after QK(i)'s kf reads; V(i+1) after PV(i)'s vf reads;
// Srel(i+1) prefetched in QK(i).  Staging is WAVE-LOCAL (wave w stages exactly
// the K rows [16w,16w+16) / V rows [64w,64w+64) it reads), so only lgkm(0) of
// the wave's own LDS reads is needed before re-staging -- no barrier.  Two raw
// s_barriers/iter (Ss handoff b2, Ps handoff b3) with lgkm-only drains: the
// in-flight global_load_lds survive the barriers (counted-vmcnt, T3/T4).
// Waits: vmcnt(9) before kf reads (drains K(i); srel(i)+V(i)=9 younger stay),
// vmcnt(9) before vf reads (drains V(i); K(i+1)+srel(i+1)=9 stay; vmcnt(0) on
// the last iter where nothing younger exists).  Issue order per wave is pinned
// (sched_barrier(0)) so the counts are deterministic.  Ss pad stays 68 (write
// 2-way free; b128 reads already at the uniform-8 floor -- R8's pad-65 regressed).
__launch_bounds__(256, 2)
__global__ void attn_kernel(const bf16* __restrict__ Qw, const bf16* __restrict__ Kw,
                            const bf16* __restrict__ Vt, const bf16* __restrict__ Srel,
                            float* __restrict__ out)
{
    __shared__ bf16  Klds[64 * 256];      // rows j (64), 32 chunks of 8, rotated
    __shared__ bf16  Vlds[256 * 64];      // rows d (256), 8 chunks of 8, rotated
    __shared__ float Ss[32][68];
    __shared__ bf16  Ps[32][72];
    __shared__ float mSt[32], lSt[32], aSt[32];

    int tid  = threadIdx.x;
    int lane = tid & 63;
    int wid  = tid >> 6;
    int l15  = lane & 15;
    int quad = lane >> 4;

    int xcd = blockIdx.x & 7;          // XCD = blockIdx % 8 (round-robin dispatch)
    int b   = xcd >> 1;
    int dh  = xcd & 1;
    int i0  = (blockIdx.x >> 3) * 32;

    const bf16* Qb = Qw + (size_t)b * LL * DKK;
    const bf16* Kb = Kw + (size_t)b * LL * DKK;
    const bf16* Sb = Srel + (size_t)b * LL * LL;
    const bf16* Vb = Vt + (size_t)(dh * 256) * (BB * LL) + (size_t)b * LL;

    bf16x8 Qreg[2][8];
    #pragma unroll
    for (int rt = 0; rt < 2; ++rt)
        #pragma unroll
        for (int ks = 0; ks < 8; ++ks)
            Qreg[rt][ks] = *(const bf16x8*)(Qb + (size_t)(i0 + rt * 16 + l15) * DKK
                                            + ks * 32 + quad * 8);

    if (tid < 32) { mSt[tid] = -1e30f; lSt[tid] = 0.f; }

    f32x4 accO[2][4];
    #pragma unroll
    for (int rt = 0; rt < 2; ++rt)
        #pragma unroll
        for (int nt = 0; nt < 4; ++nt) accO[rt][nt] = 0;

    // drain Qreg loads before the counted staging stream starts
    asm volatile("s_waitcnt vmcnt(0)" ::: "memory");

    // ---- prologue (issue order defines vmcnt counts): K0(8), srel0(1), V0(8)
    STAGE_K(0);
    __builtin_amdgcn_sched_barrier(0);
    int srow = i0 + (tid >> 3), ssg = tid & 7;
    bf16x8 srelCur = *(const bf16x8*)(Sb + (size_t)srow * LL + ssg * 8);
    __builtin_amdgcn_sched_barrier(0);
    STAGE_V(0);

    for (int j0 = 0; j0 < LL; j0 += 64) {
        int jn = j0 + 64;
        bool notlast = (jn < LL);

        // ===== QK phase =====
        asm volatile("s_waitcnt vmcnt(9)" ::: "memory");   // K(i) staged
        bf16x8 kf[8];
        int jrow = wid * 16 + l15;
        #pragma unroll
        for (int ks = 0; ks < 8; ++ks) {
            int cp = (ks * 4 + quad + jrow) & 31;
            kf[ks] = *(const bf16x8*)&Klds[jrow * 256 + cp * 8];
        }
        asm volatile("s_waitcnt lgkmcnt(0)" ::: "memory"); // own kf reads done
        __builtin_amdgcn_sched_barrier(0);
        if (notlast) { STAGE_K(jn); }                      // K(i+1) in flight
        __builtin_amdgcn_sched_barrier(0);
        bf16x8 srelNext;
        if (notlast)                                       // srel(i+1) in flight
            srelNext = *(const bf16x8*)(Sb + (size_t)srow * LL + jn + ssg * 8);
        __builtin_amdgcn_sched_barrier(0);
        f32x4 s0 = 0, s1 = 0;
        __builtin_amdgcn_s_setprio(1);
        #pragma unroll
        for (int ks = 0; ks < 8; ++ks) {
            s0 = __builtin_amdgcn_mfma_f32_16x16x32_bf16(Qreg[0][ks], kf[ks], s0, 0, 0, 0);
            s1 = __builtin_amdgcn_mfma_f32_16x16x32_bf16(Qreg[1][ks], kf[ks], s1, 0, 0, 0);
        }
        __builtin_amdgcn_s_setprio(0);
        #pragma unroll
        for (int r = 0; r < 4; ++r) {
            Ss[quad * 4 + r][wid * 16 + l15]      = s0[r];
            Ss[16 + quad * 4 + r][wid * 16 + l15] = s1[r];
        }
        asm volatile("s_waitcnt lgkmcnt(0)\ns_barrier" ::: "memory");   // b2: Ss handoff

        // ===== softmax =====
        {
            int r = tid >> 3, sg = tid & 7;
            int i = i0 + r;
            float v[8];
            #pragma unroll
            for (int c = 0; c < 8; ++c) {
                float sr = (j0 + sg * 8 + c == i + 1) ? 0.f : (float)srelCur[c];
                v[c] = (Ss[r][sg * 8 + c] + sr) * 0.0625f;
            }
            float tmax = v[0];
            #pragma unroll
            for (int c = 1; c < 8; ++c) tmax = fmaxf(tmax, v[c]);
            tmax = fmaxf(tmax, __shfl_xor(tmax, 1));
            tmax = fmaxf(tmax, __shfl_xor(tmax, 2));
            tmax = fmaxf(tmax, __shfl_xor(tmax, 4));
            float mOld = mSt[r], lOld = lSt[r];
            float mNew = fmaxf(mOld, tmax);
            float alpha = __expf(mOld - mNew);
            float ps = 0.f;
            bf16x8 pv;
            #pragma unroll
            for (int c = 0; c < 8; ++c) {
                float p = __expf(v[c] - mNew);
                ps += p;
                pv[c] = (bf16)p;
            }
            ps += __shfl_xor(ps, 1);
            ps += __shfl_xor(ps, 2);
            ps += __shfl_xor(ps, 4);
            *(bf16x8*)&Ps[r][sg * 8] = pv;
            if (sg == 0) { mSt[r] = mNew; lSt[r] = alpha * lOld + ps; aSt[r] = alpha; }
        }
        srelCur = srelNext;
        asm volatile("s_waitcnt lgkmcnt(0)\ns_barrier" ::: "memory");   // b3: Ps handoff

        // ===== PV phase =====
        if (notlast) asm volatile("s_waitcnt vmcnt(9)" ::: "memory");   // V(i) staged
        else         asm volatile("s_waitcnt vmcnt(0)" ::: "memory");
        bf16x8 aF[2][2];
        #pragma unroll
        for (int rt = 0; rt < 2; ++rt)
            #pragma unroll
            for (int kk = 0; kk < 2; ++kk)
                aF[rt][kk] = *(const bf16x8*)&Ps[rt * 16 + l15][kk * 32 + quad * 8];
        float ar[2][4];
        #pragma unroll
        for (int rt = 0; rt < 2; ++rt)
            #pragma unroll
            for (int r = 0; r < 4; ++r) ar[rt][r] = aSt[rt * 16 + quad * 4 + r];
        bf16x8 vf[4][2];
        #pragma unroll
        for (int nt = 0; nt < 4; ++nt) {
            int dd = wid * 64 + nt * 16 + l15;
            int c0 = (quad + dd) & 7;
            int c1 = (4 + quad + dd) & 7;
            vf[nt][0] = *(const bf16x8*)&Vlds[dd * 64 + c0 * 8];
            vf[nt][1] = *(const bf16x8*)&Vlds[dd * 64 + c1 * 8];
        }
        asm volatile("s_waitcnt lgkmcnt(0)" ::: "memory"); // own Ps/vf reads done
        __builtin_amdgcn_sched_barrier(0);
        if (notlast) { STAGE_V(jn); }                      // V(i+1) in flight
        __builtin_amdgcn_sched_barrier(0);
        __builtin_amdgcn_s_setprio(1);
        #pragma unroll
        for (int nt = 0; nt < 4; ++nt) {
            #pragma unroll
            for (int rt = 0; rt < 2; ++rt) {
                f32x4 o = accO[rt][nt];
                o[0] *= ar[rt][0]; o[1] *= ar[rt][1];
                o[2] *= ar[rt][2]; o[3] *= ar[rt][3];
                o = __builtin_amdgcn_mfma_f32_16x16x32_bf16(aF[rt][0], vf[nt][0], o, 0, 0, 0);
                o = __builtin_amdgcn_mfma_f32_16x16x32_bf16(aF[rt][1], vf[nt][1], o, 0, 0, 0);
                accO[rt][nt] = o;
            }
        }
        __builtin_amdgcn_s_setprio(0);
        // no trailing barrier: Ss WAR covered by b3(i), Ps/aSt WAR by b2(i+1)
    }
    float lr[2][4];
    #pragma unroll
    for (int rt = 0; rt < 2; ++rt)
        #pragma unroll
        for (int r = 0; r < 4; ++r) lr[rt][r] = 1.f / lSt[rt * 16 + quad * 4 + r];
    #pragma unroll
    for (int rt = 0; rt < 2; ++rt)
        #pragma unroll
        for (int nt = 0; nt < 4; ++nt)
            #pragma unroll
            for (int r = 0; r < 4; ++r) {
                int i = i0 + rt * 16 + quad * 4 + r;
                int d = dh * 256 + wid * 64 + nt * 16 + l15;
                out[((size_t)b * LL + i) * DD + d] = accO[rt][nt][r] * lr[rt][r];
            }
}

extern "C" void kernel_launch(void* const* d_in, const int* in_sizes, int n_in,
                              void* d_out, int out_size, void* d_ws, size_t ws_size,
                              hipStream_t stream) {
    const float* inQ = (const float*)d_in[0];
    const float* inK = (const float*)d_in[1];
    const float* inV = (const float*)d_in[2];
    const float* Wq  = (const float*)d_in[3];
    const float* Wk  = (const float*)d_in[4];
    const float* Wv  = (const float*)d_in[5];
    const float* E   = (const float*)d_in[6];
    float* out = (float*)d_out;

    char* ws = (char*)d_ws;
    bf16* Qw   = (bf16*)(ws);                         // 4 MB  [B*L][DK]
    bf16* Kw   = (bf16*)(ws + ((size_t)4  << 20));    // 4 MB  [B*L][DK]
    bf16* Vt   = (bf16*)(ws + ((size_t)8  << 20));    // 8 MB  [D][B*L]
    bf16* SrelW= (bf16*)(ws + ((size_t)16 << 20));    // 32 MB [B,L,L] skewed
    // transient buffers inside the Srel region (dead before QE writes Srel):
    bf16* Xq   = (bf16*)(ws + ((size_t)16 << 20));    // 8 MB  inQ as bf16
    bf16* Xk   = (bf16*)(ws + ((size_t)24 << 20));    // 8 MB
    bf16* Xv   = (bf16*)(ws + ((size_t)32 << 20));    // 8 MB
    bf16* Vw   = (bf16*)(ws + ((size_t)40 << 20));    // 8 MB  V row-major
    bf16* WqT  = (bf16*)(ws + ((size_t)48 << 20));            // [DK][D]
    bf16* WkT  = (bf16*)(ws + ((size_t)48 << 20) + 262144);   // [DK][D]
    bf16* WvT  = (bf16*)(ws + ((size_t)48 << 20) + 524288);   // [D][D]
    bf16* Eb   = (bf16*)(ws + ((size_t)49 << 20));            // [L][DK]

    conv3_f32_bf16<<<dim3(4096, 3), 256, 0, stream>>>(inQ, inK, inV, Xq, Xk, Xv,
                                                      (BB * LL * DD) / 4);
    conv_f32_bf16v<<<512,  256, 0, stream>>>(E, Eb, (LL * DKK) / 4);
    transpose_f32_bf16<<<512,  256, 0, stream>>>(Wq, WqT, DD, DKK);
    transpose_f32_bf16<<<512,  256, 0, stream>>>(Wk, WkT, DD, DKK);
    transpose_f32_bf16<<<1024, 256, 0, stream>>>(Wv, WvT, DD, DD);

    // Q = Xq·Wq^T' and K = Xk·Wk^T' fused via blockIdx.y: M=8192 N=256 K=512
    gemm128<0><<<dim3(2 * 64, 2),  256, 0, stream>>>(Xq, WqT, Qw, DKK, DD,
                                                     4194304L, 131072L, 2097152L);
    // Vw = Xv·Wv^T': M=8192 N=512 K=512
    gemm128<0><<<dim3(4 * 64, 1),  256, 0, stream>>>(Xv, WvT, Vw, DD, DD, 0, 0, 0);
    // Vt = Vw^T  [512][8192]
    transpose_bf16_tile<<<(DD / 64) * (BB * LL / 64), 256, 0, stream>>>(Vw, Vt, BB * LL, DD);
    // Srel (skewed) = skew(Q·E^T): per-batch M=N=2048 K=256
    gemm128<1><<<dim3(16 * 16, BB), 256, 0, stream>>>(Qw, Eb, SrelW, LL, DKK,
                                                      (long)LL * DKK, 0, (long)LL * LL);
    attn_kernel<<<dim3(BB * 64 * 2), 256, 0, stream>>>(Qw, Kw, Vt, SrelW, out);
}